// Round 1
// baseline (47.842 us; speedup 1.0000x reference)
//
#include <hip/hip_runtime.h>

// HeteroSoap: c[s][n][a][b] = sum_{atoms of species s} f_n * Y_ab  (256 floats),
// then p[a,b,n,m,l] contraction (1024 outputs).
// Kernel 1: 4 waves/block, wave w accumulates species w over the block's atom
// chunks (all 4 waves scan the same atoms; non-matching lanes contribute 0).
// Kernel 2: finalize contraction.

__global__ void __launch_bounds__(256) soap_accum(
    const float* __restrict__ coo, const int* __restrict__ numbers,
    int N, float* __restrict__ c_out)
{
    const int lane = threadIdx.x & 63;
    const int spec = threadIdx.x >> 6;   // wave id == species (NSPEC==4 waves)

    float acc[64];
#pragma unroll
    for (int j = 0; j < 64; ++j) acc[j] = 0.f;

    const int stride = gridDim.x * 64;
    for (int i0 = blockIdx.x * 64; i0 < N; i0 += stride) {
        int i = i0 + lane;
        int ic = i < N ? i : N - 1;
        float x = coo[3 * ic + 0] * 0.5f;   // xyz = coo / UNIT, UNIT = 2
        float y = coo[3 * ic + 1] * 0.5f;
        float z = coo[3 * ic + 2] * 0.5f;
        int num = numbers[ic];

        float r2 = x * x + y * y + z * z;   // scaled d^2
        float ds = sqrtf(r2);               // scaled distance; dist = 2*ds
        float t = 1.f - ds * (1.f / 3.f);   // 1 - dist/RC
        float cut = (ds < 3.f) ? t * t : 0.f;
        float r = __expf(-0.5f * r2) * cut; // exp(-0.5 dist^2/UNIT^2) * polycut
        if (i >= N || num != spec) r = 0.f; // species mask + tail mask

        float f0 = r, f1 = r * r2, f2 = f1 * r2, f3 = f2 * r2; // r * d^{2k}

        // Solid harmonics, packed: Y[l][l-m]=Re(l,m), Y[l-m][l]=Im(l,m) (m>0)
        const float Y00 = 0.28209479177387814f;
        float re11 = -0.34549414947133550f * x;   // C1*Y00, C1=-sqrt(3/2)
        float im11 = -0.34549414947133550f * y;
        float re10 =  0.48860251190291992f * z;   // G1*Y00, G1=sqrt(3)
        float re22 = -1.11803398874989490f * (x * re11 - y * im11); // -sqrt(5)/2
        float im22 = -1.11803398874989490f * (x * im11 + y * re11);
        float re21 =  2.23606797749978970f * z * re11;              // sqrt(5)
        float im21 =  2.23606797749978970f * z * im11;
        float re20 =  1.93649167310370850f * (z * re10 - 0.16286750396763996f * r2); // A20*(z*re10 - B20*Y00*r2)
        float re33 = -1.08012344973464350f * (x * re22 - y * im22); // -sqrt(7/6)
        float im33 = -1.08012344973464350f * (x * im22 + y * re22);
        float re32 =  2.64575131106459070f * z * re22;              // sqrt(7)
        float im32 =  2.64575131106459070f * z * im22;
        float re31 =  2.09165006633518890f * (z * re21 - 0.44721359549995793f * r2 * re11); // A31, B31
        float im31 =  2.09165006633518890f * (z * im21 - 0.44721359549995793f * r2 * im11);
        float re30 =  1.97202659436653870f * (z * re20 - 0.51639777949432220f * r2 * re10); // A30, B30

        float Y[16];
        Y[0] = Y00;  Y[1] = im11;  Y[2]  = im22;  Y[3]  = im33;
        Y[4] = re11; Y[5] = re10;  Y[6]  = im21;  Y[7]  = im32;
        Y[8] = re22; Y[9] = re21;  Y[10] = re20;  Y[11] = im31;
        Y[12] = re33; Y[13] = re32; Y[14] = re31; Y[15] = re30;

#pragma unroll
        for (int j = 0; j < 16; ++j) {
            acc[j]      += f0 * Y[j];
            acc[16 + j] += f1 * Y[j];
            acc[32 + j] += f2 * Y[j];
            acc[48 + j] += f3 * Y[j];
        }
    }

    // Fold-butterfly: after 6 steps lane t holds sum over lanes of acc[t].
    // All register indices compile-time; runtime lane bit only selects values.
#define RSTEP(BIT) \
    { _Pragma("unroll") \
      for (int j = 0; j < BIT; ++j) { \
          bool hi = (lane & BIT) != 0; \
          float mine = hi ? acc[j + BIT] : acc[j]; \
          float send = hi ? acc[j] : acc[j + BIT]; \
          acc[j] = mine + __shfl_xor(send, BIT, 64); \
      } }
    RSTEP(32) RSTEP(16) RSTEP(8) RSTEP(4) RSTEP(2) RSTEP(1)
#undef RSTEP

    atomicAdd(&c_out[spec * 64 + lane], acc[0]);
}

// p1[a,b,n,m,l] = sum_{j<=l} w_j c[b,m,l,j] c[a,n,l,j]   (w = 1 if j==l else 2)
// p2[a,b,n,m,l] = sum_{i<l}  2  c[b,m,i,l] c[a,n,i,l]
// out = (p1+p2) * nnl[n,m,l]
__global__ void soap_finalize(const float* __restrict__ c, float* __restrict__ out)
{
    __shared__ float cs[256];
    int t = threadIdx.x;
    if (t < 256) cs[t] = c[t];
    __syncthreads();

    int l = t & 3, m = (t >> 2) & 3, n = (t >> 4) & 3, b = (t >> 6) & 3, a = (t >> 8) & 3;
    const float* cbm = &cs[(b * 4 + m) * 16];
    const float* can = &cs[(a * 4 + n) * 16];

    float v = 0.f;
    for (int j = 0; j <= l; ++j) {
        float w = (j == l) ? 1.f : 2.f;
        v += w * cbm[l * 4 + j] * can[l * 4 + j];
    }
    for (int i = 0; i < l; ++i)
        v += 2.f * cbm[i * 4 + l] * can[i * 4 + l];

    // nnl[n,m,l] = sqrt(a_nl * a_ml), a_nl = 1/((2l+1) 2^(2n+l) n! (n+l)!)
    const float fact[7] = {1.f, 1.f, 2.f, 6.f, 24.f, 120.f, 720.f};
    float an = 1.0f / ((float)(2 * l + 1) * (float)(1 << (2 * n + l)) * fact[n] * fact[n + l]);
    float am = 1.0f / ((float)(2 * l + 1) * (float)(1 << (2 * m + l)) * fact[m] * fact[m + l]);
    out[t] = v * sqrtf(an * am);
}

extern "C" void kernel_launch(void* const* d_in, const int* in_sizes, int n_in,
                              void* d_out, int out_size, void* d_ws, size_t ws_size,
                              hipStream_t stream)
{
    const float* coo = (const float*)d_in[0];
    const int* numbers = (const int*)d_in[1];
    int N = in_sizes[1];            // 1,000,000 atoms
    float* c_ws = (float*)d_ws;     // 256-float species-grouped moment buffer

    hipMemsetAsync(c_ws, 0, 256 * sizeof(float), stream);   // capture-safe
    hipLaunchKernelGGL(soap_accum, dim3(1024), dim3(256), 0, stream,
                       coo, numbers, N, c_ws);
    hipLaunchKernelGGL(soap_finalize, dim3(1), dim3(1024), 0, stream,
                       c_ws, (float*)d_out);
}

// Round 2
// 37.911 us; speedup vs baseline: 1.2619x; 1.2619x over previous
//
#include <hip/hip_runtime.h>

// HeteroSoap: c[s][n][a][b] = sum_{atoms of species s} f_n * Y_ab  (256 floats),
// then p[a,b,n,m,l] contraction (1024 outputs).
// Stage 1: 4 waves/block, wave w accumulates species w; per-block partials
//          written WITHOUT atomics (round-0 atomic tail cost ~30us).
// Stage 2: 16-block tree reduction of partials -> c (64 atomics/address max).
// Stage 3: finalize contraction (1 block).

__device__ __forceinline__ void soap_atom(
    const float* __restrict__ coo, const int* __restrict__ numbers,
    int N, int spec, int i, float acc[64])
{
    int ic = i < N ? i : N - 1;
    float x = coo[3 * ic + 0] * 0.5f;   // xyz = coo / UNIT, UNIT = 2
    float y = coo[3 * ic + 1] * 0.5f;
    float z = coo[3 * ic + 2] * 0.5f;
    int num = numbers[ic];

    float r2 = x * x + y * y + z * z;   // scaled d^2
    float ds = sqrtf(r2);               // scaled distance; dist = 2*ds
    float t = 1.f - ds * (1.f / 3.f);   // 1 - dist/RC
    float cut = (ds < 3.f) ? t * t : 0.f;
    float r = __expf(-0.5f * r2) * cut; // exp(-0.5 dist^2/UNIT^2) * polycut
    if (i >= N || num != spec) r = 0.f; // species mask + tail mask

    float f0 = r, f1 = r * r2, f2 = f1 * r2, f3 = f2 * r2; // r * d^{2k}

    // Solid harmonics, packed: Y[l][l-m]=Re(l,m), Y[l-m][l]=Im(l,m) (m>0)
    const float Y00 = 0.28209479177387814f;
    float re11 = -0.34549414947133550f * x;   // C1*Y00, C1=-sqrt(3/2)
    float im11 = -0.34549414947133550f * y;
    float re10 =  0.48860251190291992f * z;   // G1*Y00, G1=sqrt(3)
    float re22 = -1.11803398874989490f * (x * re11 - y * im11); // -sqrt(5)/2
    float im22 = -1.11803398874989490f * (x * im11 + y * re11);
    float re21 =  2.23606797749978970f * z * re11;              // sqrt(5)
    float im21 =  2.23606797749978970f * z * im11;
    float re20 =  1.93649167310370850f * (z * re10 - 0.16286750396763996f * r2);
    float re33 = -1.08012344973464350f * (x * re22 - y * im22); // -sqrt(7/6)
    float im33 = -1.08012344973464350f * (x * im22 + y * re22);
    float re32 =  2.64575131106459070f * z * re22;              // sqrt(7)
    float im32 =  2.64575131106459070f * z * im22;
    float re31 =  2.09165006633518890f * (z * re21 - 0.44721359549995793f * r2 * re11);
    float im31 =  2.09165006633518890f * (z * im21 - 0.44721359549995793f * r2 * im11);
    float re30 =  1.97202659436653870f * (z * re20 - 0.51639777949432220f * r2 * re10);

    float Y[16];
    Y[0] = Y00;  Y[1] = im11;  Y[2]  = im22;  Y[3]  = im33;
    Y[4] = re11; Y[5] = re10;  Y[6]  = im21;  Y[7]  = im32;
    Y[8] = re22; Y[9] = re21;  Y[10] = re20;  Y[11] = im31;
    Y[12] = re33; Y[13] = re32; Y[14] = re31; Y[15] = re30;

#pragma unroll
    for (int j = 0; j < 16; ++j) {
        acc[j]      += f0 * Y[j];
        acc[16 + j] += f1 * Y[j];
        acc[32 + j] += f2 * Y[j];
        acc[48 + j] += f3 * Y[j];
    }
}

__global__ void __launch_bounds__(256) soap_accum(
    const float* __restrict__ coo, const int* __restrict__ numbers,
    int N, int nb, float* __restrict__ partials)
{
    const int lane = threadIdx.x & 63;
    const int spec = threadIdx.x >> 6;   // wave id == species (NSPEC==4 waves)

    float acc[64];
#pragma unroll
    for (int j = 0; j < 64; ++j) acc[j] = 0.f;

    const int stride = nb * 128;         // 2 atoms / lane / iteration
    for (int i0 = blockIdx.x * 128; i0 < N; i0 += stride) {
        soap_atom(coo, numbers, N, spec, i0 + lane, acc);
        soap_atom(coo, numbers, N, spec, i0 + 64 + lane, acc);
    }

    // Fold-butterfly: after 6 steps lane t holds sum over lanes of acc[t].
#define RSTEP(BIT) \
    { _Pragma("unroll") \
      for (int j = 0; j < BIT; ++j) { \
          bool hi = (lane & BIT) != 0; \
          float mine = hi ? acc[j + BIT] : acc[j]; \
          float send = hi ? acc[j] : acc[j + BIT]; \
          acc[j] = mine + __shfl_xor(send, BIT, 64); \
      } }
    RSTEP(32) RSTEP(16) RSTEP(8) RSTEP(4) RSTEP(2) RSTEP(1)
#undef RSTEP

    // Per-block partial: element index spec*64+lane == threadIdx.x. No atomics.
    partials[blockIdx.x * 256 + threadIdx.x] = acc[0];
}

__global__ void __launch_bounds__(256) soap_reduce(
    const float* __restrict__ partials, int nb, float* __restrict__ c)
{
    int t = threadIdx.x;
    float v = 0.f;
    for (int r = blockIdx.x; r < nb; r += gridDim.x)
        v += partials[r * 256 + t];           // consecutive t -> coalesced
    atomicAdd(&c[t], v);                      // <=64 atomics per address
}

// p1[a,b,n,m,l] = sum_{j<=l} w_j c[b,m,l,j] c[a,n,l,j]   (w = 1 if j==l else 2)
// p2[a,b,n,m,l] = sum_{i<l}  2  c[b,m,i,l] c[a,n,i,l]
// out = (p1+p2) * nnl[n,m,l]
__global__ void soap_finalize(const float* __restrict__ c, float* __restrict__ out)
{
    __shared__ float cs[256];
    int t = threadIdx.x;
    if (t < 256) cs[t] = c[t];
    __syncthreads();

    int l = t & 3, m = (t >> 2) & 3, n = (t >> 4) & 3, b = (t >> 6) & 3, a = (t >> 8) & 3;
    const float* cbm = &cs[(b * 4 + m) * 16];
    const float* can = &cs[(a * 4 + n) * 16];

    float v = 0.f;
    for (int j = 0; j <= l; ++j) {
        float w = (j == l) ? 1.f : 2.f;
        v += w * cbm[l * 4 + j] * can[l * 4 + j];
    }
    for (int i = 0; i < l; ++i)
        v += 2.f * cbm[i * 4 + l] * can[i * 4 + l];

    const float fact[7] = {1.f, 1.f, 2.f, 6.f, 24.f, 120.f, 720.f};
    float an = 1.0f / ((float)(2 * l + 1) * (float)(1 << (2 * n + l)) * fact[n] * fact[n + l]);
    float am = 1.0f / ((float)(2 * l + 1) * (float)(1 << (2 * m + l)) * fact[m] * fact[m + l]);
    out[t] = v * sqrtf(an * am);
}

extern "C" void kernel_launch(void* const* d_in, const int* in_sizes, int n_in,
                              void* d_out, int out_size, void* d_ws, size_t ws_size,
                              hipStream_t stream)
{
    const float* coo = (const float*)d_in[0];
    const int* numbers = (const int*)d_in[1];
    int N = in_sizes[1];                 // 1,000,000 atoms

    float* c_ws = (float*)d_ws;          // [256] stage-2 result
    float* partials = c_ws + 256;        // [nb*256] per-block partials

    // nb blocks of partials must fit in ws: (256 + nb*256)*4 bytes
    long cap = (long)(ws_size / 1024) - 1;   // ws_size/(256*4) - 1
    int nb = (int)(cap < 1 ? 1 : (cap > 1024 ? 1024 : cap));

    hipMemsetAsync(c_ws, 0, 256 * sizeof(float), stream);
    hipLaunchKernelGGL(soap_accum, dim3(nb), dim3(256), 0, stream,
                       coo, numbers, N, nb, partials);
    hipLaunchKernelGGL(soap_reduce, dim3(16), dim3(256), 0, stream,
                       partials, nb, c_ws);
    hipLaunchKernelGGL(soap_finalize, dim3(1), dim3(1024), 0, stream,
                       c_ws, (float*)d_out);
}

// Round 3
// 33.465 us; speedup vs baseline: 1.4296x; 1.1328x over previous
//
#include <hip/hip_runtime.h>

// HeteroSoap: c[s][n][a][b] = sum_{atoms of species s} f_n * Y_ab  (256 floats),
// then p[a,b,n,m,l] contraction (1024 outputs).
// Stage 1 (soap_accum, nb=2048 blocks): 4 waves/block, wave w = species w;
//         per-block partials, no atomics. 8 blocks/CU -> 32 waves/CU.
// Stage 2 (soap_reduce, 32 blocks): non-atomic tree step, 2 MB -> 32 KB.
// Stage 3 (soap_finalize, 1 block): sum 32 rows in-LDS + contraction.

__device__ __forceinline__ void soap_atom(
    const float* __restrict__ coo, const int* __restrict__ numbers,
    int N, int spec, int i, float acc[64])
{
    int ic = i < N ? i : N - 1;
    float x = coo[3 * ic + 0] * 0.5f;   // xyz = coo / UNIT, UNIT = 2
    float y = coo[3 * ic + 1] * 0.5f;
    float z = coo[3 * ic + 2] * 0.5f;
    int num = numbers[ic];

    float r2 = x * x + y * y + z * z;   // scaled d^2
    float ds = sqrtf(r2);               // scaled distance; dist = 2*ds
    float t = 1.f - ds * (1.f / 3.f);   // 1 - dist/RC
    float cut = (ds < 3.f) ? t * t : 0.f;
    float r = __expf(-0.5f * r2) * cut; // exp(-0.5 dist^2/UNIT^2) * polycut
    if (i >= N || num != spec) r = 0.f; // species mask + tail mask

    float f0 = r, f1 = r * r2, f2 = f1 * r2, f3 = f2 * r2; // r * d^{2k}

    // Solid harmonics, packed: Y[l][l-m]=Re(l,m), Y[l-m][l]=Im(l,m) (m>0)
    const float Y00 = 0.28209479177387814f;
    float re11 = -0.34549414947133550f * x;   // C1*Y00, C1=-sqrt(3/2)
    float im11 = -0.34549414947133550f * y;
    float re10 =  0.48860251190291992f * z;   // G1*Y00, G1=sqrt(3)
    float re22 = -1.11803398874989490f * (x * re11 - y * im11); // -sqrt(5)/2
    float im22 = -1.11803398874989490f * (x * im11 + y * re11);
    float re21 =  2.23606797749978970f * z * re11;              // sqrt(5)
    float im21 =  2.23606797749978970f * z * im11;
    float re20 =  1.93649167310370850f * (z * re10 - 0.16286750396763996f * r2);
    float re33 = -1.08012344973464350f * (x * re22 - y * im22); // -sqrt(7/6)
    float im33 = -1.08012344973464350f * (x * im22 + y * re22);
    float re32 =  2.64575131106459070f * z * re22;              // sqrt(7)
    float im32 =  2.64575131106459070f * z * im22;
    float re31 =  2.09165006633518890f * (z * re21 - 0.44721359549995793f * r2 * re11);
    float im31 =  2.09165006633518890f * (z * im21 - 0.44721359549995793f * r2 * im11);
    float re30 =  1.97202659436653870f * (z * re20 - 0.51639777949432220f * r2 * re10);

    float Y[16];
    Y[0] = Y00;  Y[1] = im11;  Y[2]  = im22;  Y[3]  = im33;
    Y[4] = re11; Y[5] = re10;  Y[6]  = im21;  Y[7]  = im32;
    Y[8] = re22; Y[9] = re21;  Y[10] = re20;  Y[11] = im31;
    Y[12] = re33; Y[13] = re32; Y[14] = re31; Y[15] = re30;

#pragma unroll
    for (int j = 0; j < 16; ++j) {
        acc[j]      += f0 * Y[j];
        acc[16 + j] += f1 * Y[j];
        acc[32 + j] += f2 * Y[j];
        acc[48 + j] += f3 * Y[j];
    }
}

__global__ void __launch_bounds__(256) soap_accum(
    const float* __restrict__ coo, const int* __restrict__ numbers,
    int N, int nb, float* __restrict__ partials)
{
    const int lane = threadIdx.x & 63;
    const int spec = threadIdx.x >> 6;   // wave id == species (NSPEC==4 waves)

    float acc[64];
#pragma unroll
    for (int j = 0; j < 64; ++j) acc[j] = 0.f;

    const int stride = nb * 128;         // 2 atoms / lane / iteration
    for (int i0 = blockIdx.x * 128; i0 < N; i0 += stride) {
        soap_atom(coo, numbers, N, spec, i0 + lane, acc);
        soap_atom(coo, numbers, N, spec, i0 + 64 + lane, acc);
    }

    // Fold-butterfly: after 6 steps lane t holds sum over lanes of acc[t].
#define RSTEP(BIT) \
    { _Pragma("unroll") \
      for (int j = 0; j < BIT; ++j) { \
          bool hi = (lane & BIT) != 0; \
          float mine = hi ? acc[j + BIT] : acc[j]; \
          float send = hi ? acc[j] : acc[j + BIT]; \
          acc[j] = mine + __shfl_xor(send, BIT, 64); \
      } }
    RSTEP(32) RSTEP(16) RSTEP(8) RSTEP(4) RSTEP(2) RSTEP(1)
#undef RSTEP

    partials[blockIdx.x * 256 + threadIdx.x] = acc[0];   // no atomics
}

__global__ void __launch_bounds__(256) soap_reduce(
    const float* __restrict__ partials, int nb, float* __restrict__ p2)
{
    int t = threadIdx.x;
    float v = 0.f;
    for (int r = blockIdx.x; r < nb; r += 32)
        v += partials[r * 256 + t];           // consecutive t -> coalesced
    p2[blockIdx.x * 256 + t] = v;             // no atomics, no memset needed
}

// p1[a,b,n,m,l] = sum_{j<=l} w_j c[b,m,l,j] c[a,n,l,j]   (w = 1 if j==l else 2)
// p2[a,b,n,m,l] = sum_{i<l}  2  c[b,m,i,l] c[a,n,i,l]
// out = (p1+p2) * nnl[n,m,l]
__global__ void __launch_bounds__(1024) soap_finalize(
    const float* __restrict__ p2, float* __restrict__ out)
{
    __shared__ float cs[256];
    int t = threadIdx.x;
    if (t < 256) {
        float v = 0.f;
#pragma unroll
        for (int b = 0; b < 32; ++b) v += p2[b * 256 + t];
        cs[t] = v;
    }
    __syncthreads();

    int l = t & 3, m = (t >> 2) & 3, n = (t >> 4) & 3, b = (t >> 6) & 3, a = (t >> 8) & 3;
    const float* cbm = &cs[(b * 4 + m) * 16];
    const float* can = &cs[(a * 4 + n) * 16];

    float v = 0.f;
    for (int j = 0; j <= l; ++j) {
        float w = (j == l) ? 1.f : 2.f;
        v += w * cbm[l * 4 + j] * can[l * 4 + j];
    }
    for (int i = 0; i < l; ++i)
        v += 2.f * cbm[i * 4 + l] * can[i * 4 + l];

    const float fact[7] = {1.f, 1.f, 2.f, 6.f, 24.f, 120.f, 720.f};
    float an = 1.0f / ((float)(2 * l + 1) * (float)(1 << (2 * n + l)) * fact[n] * fact[n + l]);
    float am = 1.0f / ((float)(2 * l + 1) * (float)(1 << (2 * m + l)) * fact[m] * fact[m + l]);
    out[t] = v * sqrtf(an * am);
}

extern "C" void kernel_launch(void* const* d_in, const int* in_sizes, int n_in,
                              void* d_out, int out_size, void* d_ws, size_t ws_size,
                              hipStream_t stream)
{
    const float* coo = (const float*)d_in[0];
    const int* numbers = (const int*)d_in[1];
    int N = in_sizes[1];                 // 1,000,000 atoms

    float* p2 = (float*)d_ws;            // [32*256] stage-2 partials
    float* partials = p2 + 32 * 256;     // [nb*256] stage-1 partials

    // (8192 + nb*256) floats must fit in ws
    long cap = (long)(ws_size / 1024) - 33;
    int nb = (int)(cap < 32 ? 32 : (cap > 2048 ? 2048 : cap));

    hipLaunchKernelGGL(soap_accum, dim3(nb), dim3(256), 0, stream,
                       coo, numbers, N, nb, partials);
    hipLaunchKernelGGL(soap_reduce, dim3(32), dim3(256), 0, stream,
                       partials, nb, p2);
    hipLaunchKernelGGL(soap_finalize, dim3(1), dim3(1024), 0, stream,
                       p2, (float*)d_out);
}

// Round 5
// 23.126 us; speedup vs baseline: 2.0687x; 1.4471x over previous
//
#include <hip/hip_runtime.h>
#include <hip/hip_bf16.h>

// HeteroSoap via MFMA: c[s*4+n][ab] = sum_atoms f_sn * Y_ab is a 16x16 GEMM
// with K = N atoms. Stage 1: each wave computes per-atom f(16,species-masked)
// and Y(16) in bf16, stages rows [atom][comp] in wave-private LDS, loads
// A/B fragments with plain scalar LDS reads (lane l&15 -> comp, 8 atoms per
// lane-group), accumulates with mfma_f32_16x16x32_bf16 (K=32 atoms/MFMA).
// Consistency: A and B fragments use the SAME (group,elem)->atom map, so the
// MFMA's internal k-order cancels in sum_k A[i][k] B[k][j]. No tr_read, no
// inline asm (round-4 failure isolated to the tr_read addressing path).
// Stage 2: 32-block tree reduce. Stage 3: Yr/Yi/nnl contraction.

typedef short short8 __attribute__((ext_vector_type(8)));
typedef float f32x4 __attribute__((ext_vector_type(4)));

__device__ __forceinline__ short bfc(float x) {
    __hip_bfloat16 h = __float2bfloat16(x);
    short s; __builtin_memcpy(&s, &h, 2); return s;
}

__global__ void __launch_bounds__(256) soap_accum(
    const float* __restrict__ coo, const int* __restrict__ numbers,
    int N, int nb, float* __restrict__ partials)
{
    __shared__ short lA[4][64][16];   // [wave][atom-row][comp]  8 KB (f matrix)
    __shared__ short lB[4][64][16];   // 8 KB (Y matrix)
    __shared__ float cred[4][256];    // 4 KB per-wave c for in-block reduce

    const int lane = threadIdx.x & 63;
    const int w = threadIdx.x >> 6;
    const int g = lane >> 4;          // k-group
    const int comp = lane & 15;       // fragment index dim (A row / B col)

    short8* wrA = (short8*)&lA[w][lane][0];
    short8* wrB = (short8*)&lB[w][lane][0];

    f32x4 acc = {0.f, 0.f, 0.f, 0.f};

    const int stride = nb * 256;      // 4 waves x 64 atoms per block per iter
    for (int base = (blockIdx.x * 4 + w) * 64; base < N; base += stride) {
        int i = base + lane;
        int ic = i < N ? i : N - 1;
        float x = coo[3 * ic + 0] * 0.5f;   // xyz = coo / UNIT, UNIT = 2
        float y = coo[3 * ic + 1] * 0.5f;
        float z = coo[3 * ic + 2] * 0.5f;
        int num = numbers[ic];

        float r2 = x * x + y * y + z * z;
        float ds = sqrtf(r2);
        float t = 1.f - ds * (1.f / 3.f);
        float cut = (ds < 3.f) ? t * t : 0.f;
        float r = __expf(-0.5f * r2) * cut;
        if (i >= N) r = 0.f;                 // tail mask (zero A row kills atom)

        float f0 = r, f1 = r * r2, f2 = f1 * r2, f3 = f2 * r2;

        // Solid harmonics, packed (L+1)x(L+1) row-major:
        const float Y00 = 0.28209479177387814f;
        float re11 = -0.34549414947133550f * x;
        float im11 = -0.34549414947133550f * y;
        float re10 =  0.48860251190291992f * z;
        float re22 = -1.11803398874989490f * (x * re11 - y * im11);
        float im22 = -1.11803398874989490f * (x * im11 + y * re11);
        float re21 =  2.23606797749978970f * z * re11;
        float im21 =  2.23606797749978970f * z * im11;
        float re20 =  1.93649167310370850f * (z * re10 - 0.16286750396763996f * r2);
        float re33 = -1.08012344973464350f * (x * re22 - y * im22);
        float im33 = -1.08012344973464350f * (x * im22 + y * re22);
        float re32 =  2.64575131106459070f * z * re22;
        float im32 =  2.64575131106459070f * z * im22;
        float re31 =  2.09165006633518890f * (z * re21 - 0.44721359549995793f * r2 * re11);
        float im31 =  2.09165006633518890f * (z * im21 - 0.44721359549995793f * r2 * im11);
        float re30 =  1.97202659436653870f * (z * re20 - 0.51639777949432220f * r2 * re10);

        short8 ylo, yhi;
        ylo[0] = bfc(Y00);  ylo[1] = bfc(im11); ylo[2] = bfc(im22); ylo[3] = bfc(im33);
        ylo[4] = bfc(re11); ylo[5] = bfc(re10); ylo[6] = bfc(im21); ylo[7] = bfc(im32);
        yhi[0] = bfc(re22); yhi[1] = bfc(re21); yhi[2] = bfc(re20); yhi[3] = bfc(im31);
        yhi[4] = bfc(re33); yhi[5] = bfc(re32); yhi[6] = bfc(re31); yhi[7] = bfc(re30);

        // f row: slots [num*4 .. num*4+3] = f0..f3, rest 0 (species one-hot)
        short h0 = bfc(f0), h1 = bfc(f1), h2 = bfc(f2), h3 = bfc(f3);
        short z0 = 0;
        short8 flo, fhi;
        flo[0] = num == 0 ? h0 : z0; flo[1] = num == 0 ? h1 : z0;
        flo[2] = num == 0 ? h2 : z0; flo[3] = num == 0 ? h3 : z0;
        flo[4] = num == 1 ? h0 : z0; flo[5] = num == 1 ? h1 : z0;
        flo[6] = num == 1 ? h2 : z0; flo[7] = num == 1 ? h3 : z0;
        fhi[0] = num == 2 ? h0 : z0; fhi[1] = num == 2 ? h1 : z0;
        fhi[2] = num == 2 ? h2 : z0; fhi[3] = num == 2 ? h3 : z0;
        fhi[4] = num == 3 ? h0 : z0; fhi[5] = num == 3 ? h1 : z0;
        fhi[6] = num == 3 ? h2 : z0; fhi[7] = num == 3 ? h3 : z0;

        // stage rows (2x ds_write_b128 per matrix); wave-private -> no barrier,
        // compiler inserts the lgkmcnt between aliasing writes and reads.
        wrA[0] = flo; wrA[1] = fhi;
        wrB[0] = ylo; wrB[1] = yhi;

        // Fragments: elem e of lane l = atom 8*g+e (+32 for MFMA1), comp l&15.
        // Same map for A and B => internal k-order irrelevant.
        short8 A0, A1, B0, B1;
#pragma unroll
        for (int e = 0; e < 8; ++e) {
            A0[e] = lA[w][8 * g + e][comp];
            A1[e] = lA[w][32 + 8 * g + e][comp];
            B0[e] = lB[w][8 * g + e][comp];
            B1[e] = lB[w][32 + 8 * g + e][comp];
        }

        acc = __builtin_amdgcn_mfma_f32_16x16x32_bf16(A0, B0, acc, 0, 0, 0);
        acc = __builtin_amdgcn_mfma_f32_16x16x32_bf16(A1, B1, acc, 0, 0, 0);
    }

    // C/D layout (m89): lane, reg r -> c[i=(lane>>4)*4+r][j=lane&15]
#pragma unroll
    for (int rr = 0; rr < 4; ++rr)
        cred[w][((lane >> 4) * 4 + rr) * 16 + (lane & 15)] = acc[rr];
    __syncthreads();

    int tt = threadIdx.x;
    partials[blockIdx.x * 256 + tt] =
        cred[0][tt] + cred[1][tt] + cred[2][tt] + cred[3][tt];
}

__global__ void __launch_bounds__(256) soap_reduce(
    const float* __restrict__ partials, int nb, float* __restrict__ p2)
{
    int t = threadIdx.x;
    float v = 0.f;
    for (int r = blockIdx.x; r < nb; r += 32)
        v += partials[r * 256 + t];
    p2[blockIdx.x * 256 + t] = v;
}

// p1[a,b,n,m,l] = sum_{j<=l} w_j c[b,m,l,j] c[a,n,l,j]   (w = 1 if j==l else 2)
// p2[a,b,n,m,l] = sum_{i<l}  2  c[b,m,i,l] c[a,n,i,l]
// out = (p1+p2) * nnl[n,m,l]
__global__ void __launch_bounds__(1024) soap_finalize(
    const float* __restrict__ p2, float* __restrict__ out)
{
    __shared__ float cs[256];
    int t = threadIdx.x;
    if (t < 256) {
        float v = 0.f;
#pragma unroll
        for (int b = 0; b < 32; ++b) v += p2[b * 256 + t];
        cs[t] = v;
    }
    __syncthreads();

    int l = t & 3, m = (t >> 2) & 3, n = (t >> 4) & 3, b = (t >> 6) & 3, a = (t >> 8) & 3;
    const float* cbm = &cs[(b * 4 + m) * 16];
    const float* can = &cs[(a * 4 + n) * 16];

    float v = 0.f;
    for (int j = 0; j <= l; ++j) {
        float wgt = (j == l) ? 1.f : 2.f;
        v += wgt * cbm[l * 4 + j] * can[l * 4 + j];
    }
    for (int i = 0; i < l; ++i)
        v += 2.f * cbm[i * 4 + l] * can[i * 4 + l];

    const float fact[7] = {1.f, 1.f, 2.f, 6.f, 24.f, 120.f, 720.f};
    float an = 1.0f / ((float)(2 * l + 1) * (float)(1 << (2 * n + l)) * fact[n] * fact[n + l]);
    float am = 1.0f / ((float)(2 * l + 1) * (float)(1 << (2 * m + l)) * fact[m] * fact[m + l]);
    out[t] = v * sqrtf(an * am);
}

extern "C" void kernel_launch(void* const* d_in, const int* in_sizes, int n_in,
                              void* d_out, int out_size, void* d_ws, size_t ws_size,
                              hipStream_t stream)
{
    const float* coo = (const float*)d_in[0];
    const int* numbers = (const int*)d_in[1];
    int N = in_sizes[1];                 // 1,000,000 atoms

    float* p2 = (float*)d_ws;            // [32*256] stage-2 partials
    float* partials = p2 + 32 * 256;     // [nb*256] stage-1 partials

    long cap = (long)(ws_size / 1024) - 33;
    int nb = (int)(cap < 32 ? 32 : (cap > 2048 ? 2048 : cap));

    hipLaunchKernelGGL(soap_accum, dim3(nb), dim3(256), 0, stream,
                       coo, numbers, N, nb, partials);
    hipLaunchKernelGGL(soap_reduce, dim3(32), dim3(256), 0, stream,
                       partials, nb, p2);
    hipLaunchKernelGGL(soap_finalize, dim3(1), dim3(1024), 0, stream,
                       p2, (float*)d_out);
}

// Round 6
// 19.111 us; speedup vs baseline: 2.5034x; 1.2101x over previous
//
#include <hip/hip_runtime.h>
#include <hip/hip_bf16.h>

// HeteroSoap via MFMA: c[s*4+n][ab] = sum_atoms f_sn * Y_ab is a 16x16 GEMM
// with K = N atoms.
// Stage 1: per-atom f(16, species one-hot) and Y(16) in bf16, staged in
// wave-private LDS TRANSPOSED [comp][atom] with XOR swizzle so each MFMA
// fragment is ONE ds_read_b128 (round-5 used 64 scalar ds_read_u16/iter ->
// LDS-pipe bound ~10us/CU). Same (lane,elem)->atom map for A and B, so the
// MFMA's internal k-order cancels in sum_k A[i][k] B[k][j].
// Stage 2: 32-block tree reduce. Stage 3: Yr/Yi/nnl contraction.

typedef short short8 __attribute__((ext_vector_type(8)));
typedef float f32x4 __attribute__((ext_vector_type(4)));

__device__ __forceinline__ short bfc(float x) {
    __hip_bfloat16 h = __float2bfloat16(x);
    short s; __builtin_memcpy(&s, &h, 2); return s;
}

// Swizzled index into a [16][64] short tile: row=comp, col=atom.
// XOR atom bits 3..5 with comp bits 0..2; write and read use the SAME map.
#define SWZ(c, a) (((c) << 6) + ((a) ^ (((c) & 7) << 3)))

__global__ void __launch_bounds__(256) soap_accum(
    const float* __restrict__ coo, const int* __restrict__ numbers,
    int N, int nb, float* __restrict__ partials)
{
    __shared__ short lT[4][2][16][64];  // [wave][A|B][comp][atom]  16 KB
    __shared__ float cred[4][256];      // 4 KB per-wave c for in-block reduce

    const int lane = threadIdx.x & 63;
    const int w = threadIdx.x >> 6;
    const int g = lane >> 4;            // k-group
    const int comp = lane & 15;         // fragment index dim (A row / B col)

    short* lAw = &lT[w][0][0][0];
    short* lBw = &lT[w][1][0][0];

    // Read addresses are loop-invariant: fragment h covers atoms 32h+8g..+7,
    // 8 contiguous (swizzled) shorts = one 16B-aligned ds_read_b128.
    const int sw = (comp & 7) << 3, cb = comp << 6;
    const short8* pA0 = (const short8*)&lAw[cb + (( 8 * g)      ^ sw)];
    const short8* pA1 = (const short8*)&lAw[cb + ((32 + 8 * g) ^ sw)];
    const short8* pB0 = (const short8*)&lBw[cb + (( 8 * g)      ^ sw)];
    const short8* pB1 = (const short8*)&lBw[cb + ((32 + 8 * g) ^ sw)];

    f32x4 acc = {0.f, 0.f, 0.f, 0.f};

    const int stride = nb * 256;        // 4 waves x 64 atoms per block per iter
    for (int base = (blockIdx.x * 4 + w) * 64; base < N; base += stride) {
        int i = base + lane;
        int ic = i < N ? i : N - 1;
        float x = coo[3 * ic + 0] * 0.5f;   // xyz = coo / UNIT, UNIT = 2
        float y = coo[3 * ic + 1] * 0.5f;
        float z = coo[3 * ic + 2] * 0.5f;
        int num = numbers[ic];

        float r2 = x * x + y * y + z * z;
        float ds = sqrtf(r2);
        float t = 1.f - ds * (1.f / 3.f);
        float cut = (ds < 3.f) ? t * t : 0.f;
        float r = __expf(-0.5f * r2) * cut;
        if (i >= N) r = 0.f;                 // tail: zero f-row kills the atom

        float f0 = r, f1 = r * r2, f2 = f1 * r2, f3 = f2 * r2;

        // Solid harmonics, packed (L+1)x(L+1) row-major:
        const float Y00 = 0.28209479177387814f;
        float re11 = -0.34549414947133550f * x;
        float im11 = -0.34549414947133550f * y;
        float re10 =  0.48860251190291992f * z;
        float re22 = -1.11803398874989490f * (x * re11 - y * im11);
        float im22 = -1.11803398874989490f * (x * im11 + y * re11);
        float re21 =  2.23606797749978970f * z * re11;
        float im21 =  2.23606797749978970f * z * im11;
        float re20 =  1.93649167310370850f * (z * re10 - 0.16286750396763996f * r2);
        float re33 = -1.08012344973464350f * (x * re22 - y * im22);
        float im33 = -1.08012344973464350f * (x * im22 + y * re22);
        float re32 =  2.64575131106459070f * z * re22;
        float im32 =  2.64575131106459070f * z * im22;
        float re31 =  2.09165006633518890f * (z * re21 - 0.44721359549995793f * r2 * re11);
        float im31 =  2.09165006633518890f * (z * im21 - 0.44721359549995793f * r2 * im11);
        float re30 =  1.97202659436653870f * (z * re20 - 0.51639777949432220f * r2 * re10);

        short yv[16];
        yv[0] = bfc(Y00);  yv[1] = bfc(im11); yv[2]  = bfc(im22); yv[3]  = bfc(im33);
        yv[4] = bfc(re11); yv[5] = bfc(re10); yv[6]  = bfc(im21); yv[7]  = bfc(im32);
        yv[8] = bfc(re22); yv[9] = bfc(re21); yv[10] = bfc(re20); yv[11] = bfc(im31);
        yv[12] = bfc(re33); yv[13] = bfc(re32); yv[14] = bfc(re31); yv[15] = bfc(re30);

        short h[4] = {bfc(f0), bfc(f1), bfc(f2), bfc(f3)};

        // Transposed swizzled stores: lane owns column `lane`; 16 comps each.
        // All indices compile-time except `lane` -> base+immediate ds_writes.
#pragma unroll
        for (int c = 0; c < 16; ++c) {
            short fv = (num == (c >> 2)) ? h[c & 3] : (short)0;
            lAw[SWZ(c, lane)] = fv;
            lBw[SWZ(c, lane)] = yv[c];
        }

        // Wave-private tile: compiler inserts lgkmcnt between the aliasing
        // writes and these vector reads (pattern proven in round 5).
        short8 A0 = *pA0, A1 = *pA1, B0 = *pB0, B1 = *pB1;

        acc = __builtin_amdgcn_mfma_f32_16x16x32_bf16(A0, B0, acc, 0, 0, 0);
        acc = __builtin_amdgcn_mfma_f32_16x16x32_bf16(A1, B1, acc, 0, 0, 0);
    }

    // C/D layout (m89): lane, reg rr -> c[i=(lane>>4)*4+rr][j=lane&15]
#pragma unroll
    for (int rr = 0; rr < 4; ++rr)
        cred[w][((lane >> 4) * 4 + rr) * 16 + (lane & 15)] = acc[rr];
    __syncthreads();

    int tt = threadIdx.x;
    partials[blockIdx.x * 256 + tt] =
        cred[0][tt] + cred[1][tt] + cred[2][tt] + cred[3][tt];
}

__global__ void __launch_bounds__(256) soap_reduce(
    const float* __restrict__ partials, int nb, float* __restrict__ p2)
{
    int t = threadIdx.x;
    float v = 0.f;
    for (int r = blockIdx.x; r < nb; r += 32)
        v += partials[r * 256 + t];
    p2[blockIdx.x * 256 + t] = v;
}

// p1[a,b,n,m,l] = sum_{j<=l} w_j c[b,m,l,j] c[a,n,l,j]   (w = 1 if j==l else 2)
// p2[a,b,n,m,l] = sum_{i<l}  2  c[b,m,i,l] c[a,n,i,l]
// out = (p1+p2) * nnl[n,m,l]
__global__ void __launch_bounds__(1024) soap_finalize(
    const float* __restrict__ p2, float* __restrict__ out)
{
    __shared__ float cs[256];
    int t = threadIdx.x;
    if (t < 256) {
        float v = 0.f;
#pragma unroll
        for (int b = 0; b < 32; ++b) v += p2[b * 256 + t];
        cs[t] = v;
    }
    __syncthreads();

    int l = t & 3, m = (t >> 2) & 3, n = (t >> 4) & 3, b = (t >> 6) & 3, a = (t >> 8) & 3;
    const float* cbm = &cs[(b * 4 + m) * 16];
    const float* can = &cs[(a * 4 + n) * 16];

    float v = 0.f;
    for (int j = 0; j <= l; ++j) {
        float wgt = (j == l) ? 1.f : 2.f;
        v += wgt * cbm[l * 4 + j] * can[l * 4 + j];
    }
    for (int i = 0; i < l; ++i)
        v += 2.f * cbm[i * 4 + l] * can[i * 4 + l];

    const float fact[7] = {1.f, 1.f, 2.f, 6.f, 24.f, 120.f, 720.f};
    float an = 1.0f / ((float)(2 * l + 1) * (float)(1 << (2 * n + l)) * fact[n] * fact[n + l]);
    float am = 1.0f / ((float)(2 * l + 1) * (float)(1 << (2 * m + l)) * fact[m] * fact[m + l]);
    out[t] = v * sqrtf(an * am);
}

extern "C" void kernel_launch(void* const* d_in, const int* in_sizes, int n_in,
                              void* d_out, int out_size, void* d_ws, size_t ws_size,
                              hipStream_t stream)
{
    const float* coo = (const float*)d_in[0];
    const int* numbers = (const int*)d_in[1];
    int N = in_sizes[1];                 // 1,000,000 atoms

    float* p2 = (float*)d_ws;            // [32*256] stage-2 partials
    float* partials = p2 + 32 * 256;     // [nb*256] stage-1 partials

    long cap = (long)(ws_size / 1024) - 33;
    int nb = (int)(cap < 32 ? 32 : (cap > 1024 ? 1024 : cap));

    hipLaunchKernelGGL(soap_accum, dim3(nb), dim3(256), 0, stream,
                       coo, numbers, N, nb, partials);
    hipLaunchKernelGGL(soap_reduce, dim3(32), dim3(256), 0, stream,
                       partials, nb, p2);
    hipLaunchKernelGGL(soap_finalize, dim3(1), dim3(1024), 0, stream,
                       p2, (float*)d_out);
}